// Round 6
// baseline (418.988 us; speedup 1.0000x reference)
//
#include <hip/hip_runtime.h>

#define B_    32
#define S_    577
#define HID_  768
#define NH_   12
#define HD_   64
#define SPAD  640
#define SB_   5            // s-blocks of 128 per batch (5*128 = 640)
#define MT_   160          // b-aligned m-tiles: 32 * 5
#define KT_   12           // 768/64
#define NT_   18           // 2304/128 (B-image panels)

typedef __attribute__((ext_vector_type(8))) short short8;
typedef __attribute__((ext_vector_type(4))) short short4s;
typedef __attribute__((ext_vector_type(4))) float float4_;

static __device__ __forceinline__ float bf2f(short s) {
    union { float f; unsigned u; } cvt;
    cvt.u = ((unsigned)(unsigned short)s) << 16;
    return cvt.f;
}
static __device__ __forceinline__ short f2bf(float f) {
    union { float f; unsigned u; } cvt;
    cvt.f = f;
    unsigned u = cvt.u;
    unsigned r = u + 0x7FFF + ((u >> 16) & 1);   // RNE; finite inputs
    return (short)(r >> 16);
}

// ---------------------------------------------------------------------------
// A image: ximg[mt=b*5+sb][kt][kg8][row128][8]  (MFMA-fragment-ordered bf16)
// ---------------------------------------------------------------------------
__global__ __launch_bounds__(256) void convA_kernel(
    const float* __restrict__ X, short* __restrict__ ximg)
{
    const int mt = blockIdx.x, kt = blockIdx.y;
    const int b = mt / SB_, sb = mt - b * SB_;
    short* img = ximg + ((size_t)mt * KT_ + kt) * 8192;
#pragma unroll
    for (int i = 0; i < 4; ++i) {
        const int j = i * 256 + threadIdx.x;   // 0..1023
        const int row = j >> 3, kg = j & 7;
        const int s = sb * 128 + row;
        const int srow = (s < S_) ? s : 0;     // pad rows: any finite
        const float* src = X + ((size_t)b * S_ + srow) * HID_ + kt * 64 + kg * 8;
        float4_ f0 = __builtin_nontemporal_load((const float4_*)src);
        float4_ f1 = __builtin_nontemporal_load((const float4_*)(src + 4));
        short8 s8;
#pragma unroll
        for (int e = 0; e < 4; ++e) { s8[e] = f2bf(f0[e]); s8[e + 4] = f2bf(f1[e]); }
        __builtin_nontemporal_store(s8, (short8*)(img + ((size_t)kg * 128 + row) * 8));
    }
}

// B image: wimg[nt18][kt][kg8][row128][8], nt = z*6 + local (row = n in tile)
__global__ __launch_bounds__(256) void convB_kernel(
    const float* __restrict__ Wq, const float* __restrict__ Wk,
    const float* __restrict__ Wv, short* __restrict__ wimg)
{
    const int nt = blockIdx.x, kt = blockIdx.y;
    const int z = nt / 6;
    const float* W = (z == 0) ? Wq : (z == 1) ? Wk : Wv;
    const int n0 = (nt - z * 6) * 128;
    short* img = wimg + ((size_t)nt * KT_ + kt) * 8192;
#pragma unroll
    for (int i = 0; i < 4; ++i) {
        const int j = i * 256 + threadIdx.x;
        const int row = j >> 3, kg = j & 7;
        const float* src = W + (size_t)(n0 + row) * HID_ + kt * 64 + kg * 8;
        float4_ f0 = __builtin_nontemporal_load((const float4_*)src);
        float4_ f1 = __builtin_nontemporal_load((const float4_*)(src + 4));
        short8 s8;
#pragma unroll
        for (int e = 0; e < 4; ++e) { s8[e] = f2bf(f0[e]); s8[e + 4] = f2bf(f1[e]); }
        __builtin_nontemporal_store(s8, (short8*)(img + ((size_t)kg * 128 + row) * 8));
    }
}

// ---------------------------------------------------------------------------
// Fused QKV GEMM, register-direct with explicit 3-deep fragment prefetch:
// phase p (24 half-K phases) computes on set(p) while sets p+1,p+2 are in
// flight -> compiler emits counted vmcnt(16), never drains. No LDS staging,
// no barriers. grid = 2880 flat (XCD-swizzled, mt-major), block 256.
// ---------------------------------------------------------------------------
#define LOADSET(S, PH) {                                                      \
    const int _p = (PH);                                                      \
    const short* _ak = ag + (size_t)(_p >> 1) * 8192;                         \
    const short* _bk = bg + (size_t)(_p >> 1) * 8192;                         \
    const int _kb = ((_p & 1) * 4 + quad) * 128;                              \
    _Pragma("unroll")                                                         \
    for (int mi = 0; mi < 4; ++mi)                                            \
        S##a[mi] = *(const short8*)(_ak + (_kb + r0 + mi * 16) * 8);          \
    _Pragma("unroll")                                                         \
    for (int g = 0; g < 4; ++g)                                               \
        S##b[g] = *(const short8*)(_bk + (_kb + c0 + g * 16) * 8);            \
}
#define MFMASET(S) {                                                          \
    __builtin_amdgcn_s_setprio(1);                                            \
    _Pragma("unroll")                                                         \
    for (int mi = 0; mi < 4; ++mi)                                            \
        _Pragma("unroll")                                                     \
        for (int g = 0; g < 4; ++g)                                           \
            acc[mi][g] = __builtin_amdgcn_mfma_f32_16x16x32_bf16(             \
                S##a[mi], S##b[g], acc[mi][g], 0, 0, 0);                      \
    __builtin_amdgcn_s_setprio(0);                                            \
}

__global__ __launch_bounds__(256) void gemm_kernel(
    const short* __restrict__ ximg, const short* __restrict__ wimg,
    const float* __restrict__ bq, const float* __restrict__ bk,
    const float* __restrict__ bv,
    const float* __restrict__ lat, const int* __restrict__ mixw,
    short* __restrict__ qo, short* __restrict__ ko, short* __restrict__ vo)
{
    __shared__ __align__(16) short eP[4][4608];   // per-wave 64x72, 36 KB

    const int bid0 = blockIdx.x;                     // 0..2879
    const int bids = (bid0 & 7) * 360 + (bid0 >> 3); // bijective (2880%8==0)
    const int mt = bids / NT_;
    const int nt = bids - mt * NT_;

    const int z   = nt / 6;
    const int nz0 = (nt - z * 6) * 128;
    const int b   = mt / SB_;
    const int s0  = (mt - b * SB_) * 128;

    const int tid  = threadIdx.x;
    const int wave = tid >> 6;
    const int lane = tid & 63;
    const int quad = lane >> 4;
    const int l16  = lane & 15;

    const short* ag = ximg + ((size_t)mt * KT_) * 8192;
    const short* bg = wimg + ((size_t)nt * KT_) * 8192;

    float4_ acc[4][4] = {};
    const int r0 = (wave & 1) * 64 + l16;
    const int c0 = (wave >> 1) * 64 + l16;

    short8 Aa[4], Ab[4], Ba[4], Bb[4], Ca[4], Cb[4];

    LOADSET(A, 0);
    LOADSET(B, 1);
    for (int it = 0; it < 4; ++it) {
        const int p = it * 6;
        LOADSET(C, p + 2);                       MFMASET(A);
        LOADSET(A, p + 3);                       MFMASET(B);
        LOADSET(B, p + 4);                       MFMASET(C);
        LOADSET(C, p + 5);                       MFMASET(A);
        LOADSET(A, (p + 6 < 24) ? p + 6 : 0);    MFMASET(B);
        LOADSET(B, (p + 7 < 24) ? p + 7 : 1);    MFMASET(C);
    }

    // -------- epilogue via per-wave LDS scratch, coalesced 16B nt stores ----
    const int mwv = *mixw;
    const float* bb = (z == 0) ? bq : (z == 1) ? bk : bv;
    const int hh   = (nz0 + (wave >> 1) * 64) >> 6;       // head 0..11
    const size_t bh = (size_t)b * NH_ + hh;
    const int sW   = s0 + (wave & 1) * 64;                // 64-aligned
    const int ch   = sW >> 6;                             // image chunk 0..9
    short* P = eP[wave];

    if (z < 2) {
        // row-major: P[s_local][d]
#pragma unroll
        for (int mi = 0; mi < 4; ++mi)
#pragma unroll
            for (int i = 0; i < 4; ++i) {
                const int ml = mi * 16 + quad * 4 + i;
                const int s  = sW + ml;
                const float* lp =
                    lat + (bh * S_ + (s < S_ ? s : S_ - 1)) * HD_;
#pragma unroll
                for (int g = 0; g < 4; ++g) {
                    const int d = g * 16 + l16;
                    float val = acc[mi][g][i] + bb[hh * 64 + d];
                    if (z == mwv) val *= __builtin_nontemporal_load(lp + d);
                    P[ml * 72 + d] = f2bf(val);
                }
            }
    } else {
        // transposed: P[d][s_local]
#pragma unroll
        for (int mi = 0; mi < 4; ++mi)
#pragma unroll
            for (int g = 0; g < 4; ++g) {
                const int d  = g * 16 + l16;
                const int mb = mi * 16 + quad * 4;
                short4s w;
#pragma unroll
                for (int i = 0; i < 4; ++i) {
                    const int s = sW + mb + i;
                    float val = acc[mi][g][i] + bb[hh * 64 + d];
                    if (mwv == 2)
                        val *= __builtin_nontemporal_load(
                            lat + (bh * S_ + (s < S_ ? s : S_ - 1)) * HD_ + d);
                    w[i] = f2bf(val);
                }
                *(short4s*)(P + d * 72 + mb) = w;
            }
    }
    // per-wave scratch: same-wave ds write->read ordering via lgkmcnt

    const int rr = lane >> 3, cc = lane & 7;
    if (z == 0) {
        short* qb = qo + (size_t)bh * SPAD * HD_;
#pragma unroll
        for (int j = 0; j < 8; ++j) {
            const int r = j * 8 + rr;                     // s_local
            __builtin_nontemporal_store(
                *(const short8*)(P + r * 72 + cc * 8),
                (short8*)(qb + (size_t)(sW + r) * 64 + cc * 8));
        }
    } else if (z == 1) {
        short* kb_ = ko + ((size_t)bh * 10 + ch) * 4096;
#pragma unroll
        for (int j = 0; j < 8; ++j) {
            const int r = j * 8 + rr;                     // s_local
            __builtin_nontemporal_store(
                *(const short8*)(P + r * 72 + cc * 8),
                (short8*)(kb_ + (cc * 64 + r) * 8));
        }
    } else {
        short* vb = vo + ((size_t)bh * 10 + ch) * 4096;
#pragma unroll
        for (int j = 0; j < 8; ++j) {
            const int r = j * 8 + rr;                     // d
            __builtin_nontemporal_store(
                *(const short8*)(P + r * 72 + cc * 8),
                (short8*)(vb + (cc * 64 + r) * 8));
        }
    }
}

// ---------------------------------------------------------------------------
// Flash attention, swapped QK^T (per-lane softmax rows) + explicit ILP:
// V fragments issued at chunk start (hidden under QK^T+softmax), K double-
// buffered one chunk ahead (hidden under softmax+PV). Zero barriers.
// grid = 3840 flat (bh-major per XCD), block 256.
// ---------------------------------------------------------------------------
#define ATTN_CHUNK(KC, KCUR, KNXT) {                                          \
    const int _kc = (KC);                                                     \
    const short* Vc = vimg + (size_t)_kc * 4096;                              \
    short8 vf[2][4];                                                          \
    _Pragma("unroll")                                                         \
    for (int c = 0; c < 2; ++c)                                               \
        _Pragma("unroll")                                                     \
        for (int g = 0; g < 4; ++g)                                           \
            vf[c][g] = *(const short8*)(Vc + (((c*4+quad)*64) + g*16 + l16)*8);\
    float4_ sc[4] = {};                                                       \
    __builtin_amdgcn_s_setprio(1);                                            \
    _Pragma("unroll")                                                         \
    for (int c = 0; c < 2; ++c)                                               \
        _Pragma("unroll")                                                     \
        for (int g = 0; g < 4; ++g)                                           \
            sc[g] = __builtin_amdgcn_mfma_f32_16x16x32_bf16(                  \
                KCUR[c][g], c ? aq1 : aq0, sc[g], 0, 0, 0);                   \
    __builtin_amdgcn_s_setprio(0);                                            \
    {   const int _kn = (_kc == 9) ? 0 : _kc + 1;                             \
        const short* Kn = kimg + (size_t)_kn * 4096;                          \
        _Pragma("unroll")                                                     \
        for (int c = 0; c < 2; ++c)                                           \
            _Pragma("unroll")                                                 \
            for (int g = 0; g < 4; ++g)                                       \
                KNXT[c][g] = *(const short8*)                                 \
                    (Kn + (((c*4+quad)*64) + g*16 + l16)*8);                  \
    }                                                                         \
    if (_kc == 9) {                                                           \
        _Pragma("unroll")                                                     \
        for (int g = 0; g < 4; ++g)                                           \
            _Pragma("unroll")                                                 \
            for (int i = 0; i < 4; ++i)                                       \
                if (576 + g * 16 + quad * 4 + i >= S_) sc[g][i] = -3.0e38f;   \
    }                                                                         \
    float cm = sc[0][0];                                                      \
    _Pragma("unroll")                                                         \
    for (int g = 0; g < 4; ++g)                                               \
        _Pragma("unroll")                                                     \
        for (int i = 0; i < 4; ++i) cm = fmaxf(cm, sc[g][i]);                 \
    cm = fmaxf(cm, __shfl_xor(cm, 16));                                       \
    cm = fmaxf(cm, __shfl_xor(cm, 32));                                       \
    const float mn    = fmaxf(m_i, cm);                                       \
    const float alpha = __expf((m_i - mn) * 0.125f);                          \
    m_i = mn;                                                                 \
    const float mo = mn * 0.125f;                                             \
    float rs = 0.0f;                                                          \
    _Pragma("unroll")                                                         \
    for (int g = 0; g < 4; ++g) {                                             \
        short4s w;                                                            \
        _Pragma("unroll")                                                     \
        for (int i = 0; i < 4; ++i) {                                         \
            const float p = __expf(__builtin_fmaf(sc[g][i], 0.125f, -mo));    \
            const short pb = f2bf(p);                                         \
            w[i] = pb;                                                        \
            rs += bf2f(pb);                                                   \
        }                                                                     \
        *(short4s*)(pw + ((g * 32 + quad * 8) ^ swz)) = w;                    \
    }                                                                         \
    rs += __shfl_xor(rs, 16);                                                 \
    rs += __shfl_xor(rs, 32);                                                 \
    l_i = l_i * alpha + rs;                                                   \
    float av[4];                                                              \
    _Pragma("unroll")                                                         \
    for (int i = 0; i < 4; ++i) av[i] = __shfl(alpha, quad * 20 + i);         \
    _Pragma("unroll")                                                         \
    for (int g = 0; g < 4; ++g)                                               \
        _Pragma("unroll")                                                     \
        for (int i = 0; i < 4; ++i) O[g][i] *= av[i];                         \
    _Pragma("unroll")                                                         \
    for (int c = 0; c < 2; ++c) {                                             \
        const short8 ap = *(const short8*)(pw + ((c * 64 + quad * 16) ^ swz));\
        __builtin_amdgcn_s_setprio(1);                                        \
        _Pragma("unroll")                                                     \
        for (int g = 0; g < 4; ++g)                                           \
            O[g] = __builtin_amdgcn_mfma_f32_16x16x32_bf16(                   \
                ap, vf[c][g], O[g], 0, 0, 0);                                 \
        __builtin_amdgcn_s_setprio(0);                                        \
    }                                                                         \
}

__global__ __launch_bounds__(256) void attn_kernel(
    const short* __restrict__ q, const short* __restrict__ k,
    const short* __restrict__ vt, float* __restrict__ out)
{
    __shared__ __align__(16) short pbuf[4][16][64];   // per-wave P, 8 KB

    const int bid0 = blockIdx.x;                      // 0..3839
    const int bids = (bid0 & 7) * 480 + (bid0 >> 3);  // bijective (3840%8==0)
    const int bh = bids / 10;
    const int qt = bids - bh * 10;

    const int b    = bh / NH_;
    const int h    = bh - b * NH_;
    const int tid  = threadIdx.x;
    const int wave = tid >> 6;
    const int lane = tid & 63;
    const int quad = lane >> 4;
    const int l16  = lane & 15;
    const int q0   = qt * 64 + wave * 16;

    const short* qp   = q  + (size_t)bh * SPAD * HD_;
    const short* kimg = k  + (size_t)bh * 40960;
    const short* vimg = vt + (size_t)bh * 40960;

    // Q fragment (used as the MFMA *B* operand; layout identical to A)
    const short8 aq0 = __builtin_nontemporal_load(
        (const short8*)(qp + (size_t)(q0 + l16) * HD_ + quad * 8));
    const short8 aq1 = __builtin_nontemporal_load(
        (const short8*)(qp + (size_t)(q0 + l16) * HD_ + 32 + quad * 8));

    float m_i = -3.0e38f, l_i = 0.0f;
    float4_ O[4] = {};

    // swizzled pbuf addressing: row = l16, key-byte x -> x ^ ((l16&7)<<4)
    char* pw = (char*)&pbuf[wave][l16][0];
    const int swz = (l16 & 7) << 4;

    short8 kfA[2][4], kfB[2][4];
#pragma unroll
    for (int c = 0; c < 2; ++c)
#pragma unroll
        for (int g = 0; g < 4; ++g)
            kfA[c][g] = *(const short8*)(kimg + (((c*4+quad)*64) + g*16 + l16)*8);

    for (int kc2 = 0; kc2 < 10; kc2 += 2) {
        ATTN_CHUNK(kc2,     kfA, kfB);
        ATTN_CHUNK(kc2 + 1, kfB, kfA);
    }

    // ---- epilogue: O row = quad*4+i, col d = g*16+l16; gather 1/l per row
    float linv[4];
#pragma unroll
    for (int i = 0; i < 4; ++i)
        linv[i] = 1.0f / __shfl(l_i, quad * 20 + i);
#pragma unroll
    for (int i = 0; i < 4; ++i) {
        const int s = q0 + quad * 4 + i;
        if (s >= S_) continue;
#pragma unroll
        for (int g = 0; g < 4; ++g)
            __builtin_nontemporal_store(
                O[g][i] * linv[i],
                out + ((size_t)b * S_ + s) * HID_ + h * HD_ + g * 16 + l16);
    }
}

extern "C" void kernel_launch(void* const* d_in, const int* in_sizes, int n_in,
                              void* d_out, int out_size, void* d_ws, size_t ws_size,
                              hipStream_t stream) {
    (void)in_sizes; (void)n_in; (void)out_size; (void)ws_size;

    const float* X   = (const float*)d_in[0];
    const float* lat = (const float*)d_in[1];
    const float* Wq  = (const float*)d_in[2];
    const float* bq  = (const float*)d_in[3];
    const float* Wk  = (const float*)d_in[4];
    const float* bk  = (const float*)d_in[5];
    const float* Wv  = (const float*)d_in[6];
    const float* bv  = (const float*)d_in[7];
    const int* mixw  = (const int*)d_in[8];
    float* out = (float*)d_out;

    const size_t per = (size_t)B_ * NH_ * SPAD * HD_;   // 15,728,640
    short* qw   = (short*)d_ws;
    short* kw   = qw + per;
    short* vw   = kw + per;
    short* wimg = vw + per;                             // 18*12*8192 = 1,769,472
    short* ximg = wimg + (size_t)NT_ * KT_ * 8192;      // 160*12*8192 = 15,728,640

    convA_kernel<<<dim3(MT_, KT_), 256, 0, stream>>>(X, ximg);
    convB_kernel<<<dim3(NT_, KT_), 256, 0, stream>>>(Wq, Wk, Wv, wimg);
    gemm_kernel<<<dim3(2880), 256, 0, stream>>>(
        ximg, wimg, bq, bk, bv, lat, mixw, qw, kw, vw);
    attn_kernel<<<dim3(3840), 256, 0, stream>>>(qw, kw, vw, out);
}